// Round 9
// baseline (125.550 us; speedup 1.0000x reference)
//
#include <hip/hip_runtime.h>

typedef unsigned long long u64;
#define EPSF 1e-6f

// ---------------- K1: conv1 1->32ch, 32x32 -> 28x28 ----------------
__global__ __launch_bounds__(512) void k_conv1(const float* __restrict__ img,
                                               const float* __restrict__ cw1,
                                               const float* __restrict__ cb1,
                                               float* __restrict__ c1) {
  int slab = blockIdx.x, b = blockIdx.y;
  __shared__ float simg[32 * 33];
  for (int k = threadIdx.x; k < 1024; k += 512) {
    int y = k >> 5, x = k & 31;
    simg[y * 33 + x] = img[b * 1024 + k];
  }
  int half = threadIdx.x >> 8;
  int u = threadIdx.x & 255;
  int ocl = u >> 5;
  int x = u & 31;
  int oc = slab * 8 + ocl;
  int y0 = half * 14;
  float w[25];
#pragma unroll
  for (int k = 0; k < 25; ++k) w[k] = cw1[oc * 25 + k];
  float bias = cb1[oc];
  __syncthreads();
  if (x < 28) {
    float acc[5];
#pragma unroll
    for (int k = 0; k < 5; ++k) acc[k] = bias;
    float* outp = c1 + (b * 32 + oc) * 784 + x;
#pragma unroll
    for (int rr = 0; rr < 18; ++rr) {
      int r = y0 + rr;
      float in[5];
#pragma unroll
      for (int c = 0; c < 5; ++c) in[c] = simg[r * 33 + x + c];
#pragma unroll
      for (int ky = 0; ky < 5; ++ky) {
        if (rr < ky || rr - ky > 13) continue;
        int slot = (rr - ky) % 5;
#pragma unroll
        for (int kx = 0; kx < 5; ++kx)
          acc[slot] = fmaf(w[ky * 5 + kx], in[kx], acc[slot]);
      }
      if (rr >= 4) {
        int slot = (rr - 4) % 5;
        outp[(y0 + rr - 4) * 28] = acc[slot];
        acc[slot] = bias;
      }
    }
  }
}

// ---------------- K2a: conv2 partials over 16-ic halves ----------------
// grid (4 ocq, 2 ichalf, 64 img) = 512 blocks, 1024 threads. LDS 52KB -> 2 blocks/CU,
// 8 waves/SIMD (full occupancy). Wave = (opair: 4 of 2 oc) x (icq: 4 of 4 ic).
// Weights wave-uniform s_loads; stride-29 LDS; conflict-free scalar staging.
// Writes bias-less partials to part[img][ichalf][32oc][576].
__global__ __launch_bounds__(1024) void k_conv2a(const float* __restrict__ c1,
                                                 const float* __restrict__ cw2,
                                                 float* __restrict__ part) {
  int ocq = blockIdx.x, ich = blockIdx.y, b = blockIdx.z;
  __shared__ float smem[12992];   // 52KB: 16 ic x [28 rows x stride 29]
  int t = threadIdx.x;
  if (t < 784) {                  // conflict-free scalar staging
    int row = t / 28, col = t % 28;
    int lofs = row * 29 + col;
    const float* src = c1 + (size_t)b * 25088 + ich * 16 * 784 + t;
#pragma unroll
    for (int ic = 0; ic < 16; ++ic) smem[ic * 812 + lofs] = src[ic * 784];
  }
  int w = __builtin_amdgcn_readfirstlane(t >> 6);
  int opair = w & 3;              // oc pair within the 8-oc slab
  int icq = w >> 2;               // 0..3, 4 ic each
  int l = t & 63;
  int py = l >> 3, px = l & 7;    // 3x3 patch origin (3py, 3px)
  int oc0 = ocq * 8 + opair * 2;
  const float* wApt = cw2 + (size_t)oc0 * 800 + (ich * 16 + icq * 4) * 25;
  const float* wBpt = wApt + 800;
  float acc[2][9];
#pragma unroll
  for (int j = 0; j < 2; ++j)
#pragma unroll
    for (int e = 0; e < 9; ++e) acc[j][e] = 0.f;
  __syncthreads();

  const float* base0 = smem + icq * 4 * 812 + (3 * py) * 29 + 3 * px;
#pragma unroll
  for (int ic = 0; ic < 4; ++ic) {
    float wa[25], wb[25];
#pragma unroll
    for (int k = 0; k < 25; ++k) { wa[k] = wApt[ic * 25 + k]; wb[k] = wBpt[ic * 25 + k]; }
    const float* base = base0 + ic * 812;
#pragma unroll
    for (int rr = 0; rr < 7; ++rr) {
      float win[7];
#pragma unroll
      for (int m = 0; m < 7; ++m) win[m] = base[rr * 29 + m];
#pragma unroll
      for (int i = 0; i < 3; ++i) {
        if (i > rr || rr - i > 4) continue;  // compile-time pruned
        int ky = rr - i;
#pragma unroll
        for (int kx = 0; kx < 5; ++kx) {
#pragma unroll
          for (int jj = 0; jj < 3; ++jj) {
            acc[0][i * 3 + jj] = fmaf(wa[ky * 5 + kx], win[jj + kx], acc[0][i * 3 + jj]);
            acc[1][i * 3 + jj] = fmaf(wb[ky * 5 + kx], win[jj + kx], acc[1][i * 3 + jj]);
          }
        }
      }
    }
  }

  __syncthreads();   // compute done -> image buffer dead, safe to alias
  float* slots = smem;                   // 2 slots x 4608 floats
  int chunk = opair * 2 * 576 + l * 9;   // lane stride 9 -> 2-way banks (free)
  if (icq >= 2) {
    float* d = slots + (icq - 2) * 4608 + chunk;
#pragma unroll
    for (int j = 0; j < 2; ++j)
#pragma unroll
      for (int e = 0; e < 9; ++e) d[j * 576 + e] = acc[j][e];
  }
  __syncthreads();
  if (icq < 2) {
    const float* s = slots + icq * 4608 + chunk;
#pragma unroll
    for (int j = 0; j < 2; ++j)
#pragma unroll
      for (int e = 0; e < 9; ++e) acc[j][e] += s[j * 576 + e];
  }
  __syncthreads();
  if (icq == 1) {
    float* d = slots + chunk;
#pragma unroll
    for (int j = 0; j < 2; ++j)
#pragma unroll
      for (int e = 0; e < 9; ++e) d[j * 576 + e] = acc[j][e];
  }
  __syncthreads();
  if (icq == 0) {
    const float* s = slots + chunk;
    float* dst = part + ((size_t)(b * 2 + ich) * 32 + oc0) * 576;
#pragma unroll
    for (int j = 0; j < 2; ++j)
#pragma unroll
      for (int i = 0; i < 3; ++i)
#pragma unroll
        for (int jj = 0; jj < 3; ++jj)
          dst[j * 576 + (3 * py + i) * 24 + 3 * px + jj] =
              acc[j][i * 3 + jj] + s[j * 576 + i * 3 + jj];
  }
}

// ---------------- K2b: sum halves + bias + 2x2 maxpool -> p1w ----------------
// 64img x 32oc x 144 pool outputs = 294912 threads -> 1152 blocks x 256.
__global__ __launch_bounds__(256) void k_conv2b(const float* __restrict__ part,
                                                const float* __restrict__ cb2,
                                                float* __restrict__ p1w) {
  int idx = blockIdx.x * 256 + threadIdx.x;
  int img = idx / 4608;
  int rem = idx % 4608;
  int oc = rem / 144;
  int pq = rem % 144;
  int PY = pq / 12, PX = pq % 12;
  const float* h0 = part + ((size_t)(img * 2 + 0) * 32 + oc) * 576 + (2 * PY) * 24 + 2 * PX;
  const float* h1 = h0 + 32 * 576;
  float bias = cb2[oc];
  float a = h0[0] + h1[0] + bias;
  float b2 = h0[1] + h1[1] + bias;
  float c = h0[24] + h1[24] + bias;
  float d = h0[25] + h1[25] + bias;
  float m = fmaxf(fmaxf(a, b2), fmaxf(c, d));
  p1w[((size_t)img * 32 + oc) * 144 + pq] = m;
}

// ---------------- K3: conv3 32->64ch, 12x12 -> 8x8 ----------------
__global__ __launch_bounds__(256) void k_conv3(const float* __restrict__ p1w,
                                               const float* __restrict__ cw3,
                                               const float* __restrict__ cb3,
                                               float* __restrict__ c3) {
  int oc8 = blockIdx.x, b = blockIdx.y;
  __shared__ float smem[11008];
  float* w3s = smem;
  float* ins = smem + 6400;
  int t = threadIdx.x;
  {
    const float4* src = (const float4*)(p1w + b * 32 * 144);
    float4* dst = (float4*)ins;
    for (int k = t; k < 1152; k += 256) dst[k] = src[k];
  }
  {
    const float4* src = (const float4*)(cw3 + oc8 * 8 * 800);
    for (int k4 = t; k4 < 1600; k4 += 256) {
      float4 v = src[k4];
      float vv[4] = {v.x, v.y, v.z, v.w};
      int k = k4 * 4;
#pragma unroll
      for (int r = 0; r < 4; ++r) {
        int kk = k + r;
        int o = kk / 800, rest = kk % 800;
        w3s[rest * 8 + o] = vv[r];
      }
    }
  }
  int g = t >> 4, p = t & 15;
  int ocg = p >> 3, row = p & 7;
  float acc[4][8];
#pragma unroll
  for (int j = 0; j < 4; ++j)
#pragma unroll
    for (int c = 0; c < 8; ++c) acc[j][c] = 0.f;
  __syncthreads();
#pragma unroll
  for (int icl = 0; icl < 2; ++icl) {
    int ic = g + icl * 16;
#pragma unroll
    for (int ky = 0; ky < 5; ++ky) {
      const float4* rp = (const float4*)(ins + ic * 144 + (row + ky) * 12);
      float win[12];
#pragma unroll
      for (int q = 0; q < 3; ++q) {
        float4 v = rp[q];
        win[4 * q] = v.x; win[4 * q + 1] = v.y; win[4 * q + 2] = v.z; win[4 * q + 3] = v.w;
      }
      const float* wb = w3s + (ic * 25 + ky * 5) * 8 + ocg * 4;
#pragma unroll
      for (int kx = 0; kx < 5; ++kx) {
        float wq[4];
        *(float4*)wq = *(const float4*)(wb + kx * 8);
#pragma unroll
        for (int c = 0; c < 8; ++c) {
#pragma unroll
          for (int j = 0; j < 4; ++j) acc[j][c] = fmaf(wq[j], win[c + kx], acc[j][c]);
        }
      }
    }
  }
  float* buf = smem;
  __syncthreads();
  if (g >= 8) {
    float* d = buf + (g - 8) * 512 + p * 32;
#pragma unroll
    for (int j = 0; j < 4; ++j)
#pragma unroll
      for (int c = 0; c < 8; ++c) d[j * 8 + c] = acc[j][c];
  }
  __syncthreads();
  if (g < 8) {
    const float* s = buf + g * 512 + p * 32;
#pragma unroll
    for (int j = 0; j < 4; ++j)
#pragma unroll
      for (int c = 0; c < 8; ++c) acc[j][c] += s[j * 8 + c];
  }
  __syncthreads();
  if (g >= 4 && g < 8) {
    float* d = buf + (g - 4) * 512 + p * 32;
#pragma unroll
    for (int j = 0; j < 4; ++j)
#pragma unroll
      for (int c = 0; c < 8; ++c) d[j * 8 + c] = acc[j][c];
  }
  __syncthreads();
  if (g < 4) {
    const float* s = buf + g * 512 + p * 32;
#pragma unroll
    for (int j = 0; j < 4; ++j)
#pragma unroll
      for (int c = 0; c < 8; ++c) acc[j][c] += s[j * 8 + c];
  }
  __syncthreads();
  if (g == 2 || g == 3) {
    float* d = buf + (g - 2) * 512 + p * 32;
#pragma unroll
    for (int j = 0; j < 4; ++j)
#pragma unroll
      for (int c = 0; c < 8; ++c) d[j * 8 + c] = acc[j][c];
  }
  __syncthreads();
  if (g < 2) {
    const float* s = buf + g * 512 + p * 32;
#pragma unroll
    for (int j = 0; j < 4; ++j)
#pragma unroll
      for (int c = 0; c < 8; ++c) acc[j][c] += s[j * 8 + c];
  }
  __syncthreads();
  if (g == 1) {
    float* d = buf + p * 32;
#pragma unroll
    for (int j = 0; j < 4; ++j)
#pragma unroll
      for (int c = 0; c < 8; ++c) d[j * 8 + c] = acc[j][c];
  }
  __syncthreads();
  if (g == 0) {
    const float* s = buf + p * 32;
#pragma unroll
    for (int j = 0; j < 4; ++j) {
      float bias = cb3[oc8 * 8 + ocg * 4 + j];
      float4 v0, v1;
      v0.x = acc[j][0] + s[j * 8 + 0] + bias; v0.y = acc[j][1] + s[j * 8 + 1] + bias;
      v0.z = acc[j][2] + s[j * 8 + 2] + bias; v0.w = acc[j][3] + s[j * 8 + 3] + bias;
      v1.x = acc[j][4] + s[j * 8 + 4] + bias; v1.y = acc[j][5] + s[j * 8 + 5] + bias;
      v1.z = acc[j][6] + s[j * 8 + 6] + bias; v1.w = acc[j][7] + s[j * 8 + 7] + bias;
      float* op = c3 + (b * 64 + oc8 * 8 + ocg * 4 + j) * 64 + row * 8;
      *(float4*)op = v0; *(float4*)(op + 4) = v1;
    }
  }
}

// ---------------- K4: conv4 64->64ch, 8x8 -> 4x4, fused pool -> emb[256] ----------------
__global__ __launch_bounds__(256) void k_conv4(const float* __restrict__ c3,
                                               const float* __restrict__ cw4,
                                               const float* __restrict__ cb4,
                                               float* __restrict__ emb) {
  int oc8 = blockIdx.x, b = blockIdx.y;
  __shared__ float smem[17152];
  float* w4s = smem;
  float* ins = smem + 12800;
  int t = threadIdx.x;
  {
    const float4* src = (const float4*)(c3 + b * 4096);
    for (int k = t; k < 1024; k += 256) {
      int ic = k >> 4, q = k & 15;
      *(float4*)(ins + ic * 68 + q * 4) = src[k];
    }
  }
  {
    const float4* src = (const float4*)(cw4 + oc8 * 8 * 1600);
    for (int k4 = t; k4 < 3200; k4 += 256) {
      float4 v = src[k4];
      float vv[4] = {v.x, v.y, v.z, v.w};
      int k = k4 * 4;
#pragma unroll
      for (int r = 0; r < 4; ++r) {
        int kk = k + r;
        int o = kk / 1600, rest = kk % 1600;
        w4s[rest * 8 + o] = vv[r];
      }
    }
  }
  int g = t >> 3, p = t & 7;
  int ocg = p >> 2, row = p & 3;
  float acc[4][4];
#pragma unroll
  for (int j = 0; j < 4; ++j)
#pragma unroll
    for (int c = 0; c < 4; ++c) acc[j][c] = 0.f;
  __syncthreads();
#pragma unroll
  for (int icl = 0; icl < 2; ++icl) {
    int ic = g + icl * 32;
#pragma unroll
    for (int ky = 0; ky < 5; ++ky) {
      const float4* rp = (const float4*)(ins + ic * 68 + (row + ky) * 8);
      float win[8];
#pragma unroll
      for (int q = 0; q < 2; ++q) {
        float4 v = rp[q];
        win[4 * q] = v.x; win[4 * q + 1] = v.y; win[4 * q + 2] = v.z; win[4 * q + 3] = v.w;
      }
      const float* wb = w4s + (ic * 25 + ky * 5) * 8 + ocg * 4;
#pragma unroll
      for (int kx = 0; kx < 5; ++kx) {
        float wq[4];
        *(float4*)wq = *(const float4*)(wb + kx * 8);
#pragma unroll
        for (int c = 0; c < 4; ++c) {
#pragma unroll
          for (int j = 0; j < 4; ++j) acc[j][c] = fmaf(wq[j], win[c + kx], acc[j][c]);
        }
      }
    }
  }
  float* buf = smem;
#pragma unroll
  for (int half = 16; half >= 1; half >>= 1) {
    __syncthreads();
    if (g >= half && g < 2 * half) {
      float* d = buf + (g - half) * 128 + p * 16;
#pragma unroll
      for (int j = 0; j < 4; ++j)
#pragma unroll
        for (int c = 0; c < 4; ++c) d[j * 4 + c] = acc[j][c];
    }
    __syncthreads();
    if (g < half) {
      const float* s = buf + g * 128 + p * 16;
#pragma unroll
      for (int j = 0; j < 4; ++j)
#pragma unroll
        for (int c = 0; c < 4; ++c) acc[j][c] += s[j * 4 + c];
    }
  }
  float* pb = buf + 2048;
  if (g == 0) {
#pragma unroll
    for (int j = 0; j < 4; ++j) {
      float bias = cb4[oc8 * 8 + ocg * 4 + j];
#pragma unroll
      for (int c = 0; c < 4; ++c) pb[(ocg * 4 + j) * 16 + row * 4 + c] = acc[j][c] + bias;
    }
  }
  __syncthreads();
  if (t < 32) {
    int o = t >> 2, q = t & 3, py = q >> 1, px = q & 1;
    const float* b0 = pb + o * 16 + (2 * py) * 4 + 2 * px;
    float m = fmaxf(fmaxf(b0[0], b0[1]), fmaxf(b0[4], b0[5]));
    emb[b * 256 + (oc8 * 8 + o) * 4 + py * 2 + px] = m;
  }
}

// ---------------- K5a: MLP heads ----------------
__global__ __launch_bounds__(256) void k_heads(const float* __restrict__ emb,
    const float* __restrict__ wc1, const float* __restrict__ bc1,
    const float* __restrict__ wc2, const float* __restrict__ bc2,
    const float* __restrict__ we1, const float* __restrict__ be1,
    const float* __restrict__ we2, const float* __restrict__ be2,
    float* __restrict__ pcw, float* __restrict__ lpcw,
    float* __restrict__ l1mw, float* __restrict__ lcatw) {
  int head = blockIdx.x, b = blockIdx.y;
  int t = threadIdx.x;
  __shared__ float e_s[256], h_s[256];
  __shared__ float aux;
  e_s[t] = emb[b * 256 + t];
  __syncthreads();
  const float* W1 = head ? we1 : wc1;
  const float* B1 = head ? be1 : bc1;
  float s = B1[t];
  for (int i = 0; i < 256; i += 4) {
    s = fmaf(e_s[i], W1[i * 256 + t], s);
    s = fmaf(e_s[i + 1], W1[(i + 1) * 256 + t], s);
    s = fmaf(e_s[i + 2], W1[(i + 2) * 256 + t], s);
    s = fmaf(e_s[i + 3], W1[(i + 3) * 256 + t], s);
  }
  h_s[t] = fmaxf(s, 0.f);
  __syncthreads();
  int NO = head ? 36 : 120;
  const float* W2 = head ? we2 : wc2;
  const float* B2 = head ? be2 : bc2;
  if (t < NO) {
    float s2 = B2[t];
    for (int i = 0; i < 256; ++i) s2 = fmaf(h_s[i], W2[i * NO + t], s2);
    float p = 1.f / (1.f + expf(-s2));
    p = fminf(fmaxf(p, EPSF), 1.f - EPSF);
    if (head == 0) {
      pcw[b * 120 + t] = p;
      lpcw[b * 120 + t] = logf(p);
      l1mw[b * 120 + t] = log1pf(-p);
    } else {
      e_s[t] = p;
    }
  }
  if (head == 1) {
    __syncthreads();
    if (t == 0) {
      float sm = 0.f;
      for (int j2 = 0; j2 < 36; ++j2) sm += e_s[j2];
      aux = sm;
    }
    __syncthreads();
    if (t < 36) lcatw[b * 36 + t] = logf(e_s[t] / aux);
  }
}

// ---------------- K5b: per-sample pass (full GPU) ----------------
__global__ __launch_bounds__(64) void k_mc1(const float* __restrict__ enoise,
    const float* __restrict__ us, const float* __restrict__ ud,
    const int* __restrict__ edges,
    const float* __restrict__ pcw, const float* __restrict__ lpcw,
    const float* __restrict__ l1mw, const float* __restrict__ lcatw,
    float* __restrict__ lw, float* __restrict__ exx) {
  int chunk = blockIdx.x, b = blockIdx.y, t = threadIdx.x;
  int s = chunk * 64 + t;
  __shared__ __align__(16) float pc_s[120];
  __shared__ __align__(16) float lpc_s[120];
  __shared__ __align__(16) float l1m_s[120];
  __shared__ __align__(16) float lcat_s[36];
  __shared__ __align__(16) int einfo[120];
  for (int k = t; k < 120; k += 64) {
    pc_s[k] = pcw[b * 120 + k];
    lpc_s[k] = lpcw[b * 120 + k];
    l1m_s[k] = l1mw[b * 120 + k];
    int u = edges[2 * k], v = edges[2 * k + 1];
    int d = v - u;
    int isV = (d == 6 || d == -6) ? 1 : 0;
    int pos = d > 0 ? u : v;
    einfo[k] = pos | (isV << 6);
  }
  if (t < 36) lcat_s[t] = lcatw[b * 36 + t];
  __syncthreads();

  float logw = 0.f;
  u64 H = 0, V = 0;
  {
    const float4* np = (const float4*)(enoise + ((size_t)(b * 256 + s)) * 120);
#pragma unroll
    for (int q = 0; q < 30; ++q) {
      float4 nz = np[q];
      float4 p4 = ((const float4*)pc_s)[q];
      float4 lp4 = ((const float4*)lpc_s)[q];
      float4 lm4 = ((const float4*)l1m_s)[q];
      int4 e4 = ((const int4*)einfo)[q];
      float nv[4] = {nz.x, nz.y, nz.z, nz.w};
      float pv[4] = {p4.x, p4.y, p4.z, p4.w};
      float lv[4] = {lp4.x, lp4.y, lp4.z, lp4.w};
      float mv[4] = {lm4.x, lm4.y, lm4.z, lm4.w};
      int ev[4] = {e4.x, e4.y, e4.z, e4.w};
#pragma unroll
      for (int r = 0; r < 4; ++r) {
        bool conn = nv[r] < pv[r];
        logw += conn ? lv[r] : mv[r];
        if (conn) {
          u64 bit = 1ull << (ev[r] & 63);
          if (ev[r] & 64) V |= bit; else H |= bit;
        }
      }
    }
  }
  int si = 0, di = 0;
  {
    const float4* up = (const float4*)(us + ((size_t)(b * 256 + s)) * 36);
    float best = -1e30f;
#pragma unroll
    for (int q = 0; q < 9; ++q) {
      float4 uv = up[q];
      float4 lc4 = ((const float4*)lcat_s)[q];
      float vv[4] = {uv.x, uv.y, uv.z, uv.w};
      float lc[4] = {lc4.x, lc4.y, lc4.z, lc4.w};
#pragma unroll
      for (int r = 0; r < 4; ++r) {
        float u = fminf(fmaxf(vv[r], EPSF), 1.f - EPSF);
        float gq = -logf(-logf(u));
        float val = lc[r] + gq;
        if (val > best) { best = val; si = q * 4 + r; }
      }
    }
  }
  {
    const float4* up = (const float4*)(ud + ((size_t)(b * 256 + s)) * 36);
    float best = -1e30f;
#pragma unroll
    for (int q = 0; q < 9; ++q) {
      float4 uv = up[q];
      float4 lc4 = ((const float4*)lcat_s)[q];
      float vv[4] = {uv.x, uv.y, uv.z, uv.w};
      float lc[4] = {lc4.x, lc4.y, lc4.z, lc4.w};
#pragma unroll
      for (int r = 0; r < 4; ++r) {
        float u = fminf(fmaxf(vv[r], EPSF), 1.f - EPSF);
        float gq = -logf(-logf(u));
        float val = lc[r] + gq;
        if (val > best) { best = val; di = q * 4 + r; }
      }
    }
  }
  logw += lcat_s[si] + lcat_s[di];

  u64 comp = 1ull << si;
  while (true) {
    u64 prev = comp;
    comp |= ((comp & H) << 1) | ((comp >> 1) & H);
    comp |= ((comp & V) << 6) | ((comp >> 6) & V);
    if (comp == prev) break;
  }
  float ex;
  if (si == di) ex = (comp != (1ull << si)) ? 1.f : 0.f;
  else ex = ((comp >> di) & 1ull) ? 1.f : 0.f;

  lw[b * 256 + s] = logw;
  exx[b * 256 + s] = ex;
}

// ---------------- K5c: softmax over samples -> output ----------------
__global__ __launch_bounds__(256) void k_mc2(const float* __restrict__ lw,
                                             const float* __restrict__ exx,
                                             float* __restrict__ out) {
  int b = blockIdx.x, t = threadIdx.x;
  __shared__ float red_s[256];
  float logw = lw[b * 256 + t];
  float ex = exx[b * 256 + t];
  red_s[t] = logw; __syncthreads();
  for (int off = 128; off > 0; off >>= 1) {
    if (t < off) red_s[t] = fmaxf(red_s[t], red_s[t + off]);
    __syncthreads();
  }
  float m = red_s[0]; __syncthreads();
  float evx = expf(logw - m);
  red_s[t] = evx; __syncthreads();
  for (int off = 128; off > 0; off >>= 1) {
    if (t < off) red_s[t] += red_s[t + off];
    __syncthreads();
  }
  float den = red_s[0]; __syncthreads();
  red_s[t] = evx * ex; __syncthreads();
  for (int off = 128; off > 0; off >>= 1) {
    if (t < off) red_s[t] += red_s[t + off];
    __syncthreads();
  }
  if (t == 0) {
    float p1v = red_s[0] / den;
    out[b * 2] = 1.f - p1v;
    out[b * 2 + 1] = p1v;
  }
}

extern "C" void kernel_launch(void* const* d_in, const int* in_sizes, int n_in,
                              void* d_out, int out_size, void* d_ws, size_t ws_size,
                              hipStream_t stream) {
  const float* image = (const float*)d_in[0];
  const float* enoise = (const float*)d_in[1];
  const float* us = (const float*)d_in[2];
  const float* udn = (const float*)d_in[3];
  const float* cw1 = (const float*)d_in[4];
  const float* cb1 = (const float*)d_in[5];
  const float* cw2 = (const float*)d_in[6];
  const float* cb2 = (const float*)d_in[7];
  const float* cw3 = (const float*)d_in[8];
  const float* cb3 = (const float*)d_in[9];
  const float* cw4 = (const float*)d_in[10];
  const float* cb4 = (const float*)d_in[11];
  const float* wc1 = (const float*)d_in[12];
  const float* bc1 = (const float*)d_in[13];
  const float* wc2 = (const float*)d_in[14];
  const float* bc2 = (const float*)d_in[15];
  const float* we1 = (const float*)d_in[16];
  const float* be1 = (const float*)d_in[17];
  const float* we2 = (const float*)d_in[18];
  const float* be2 = (const float*)d_in[19];
  const int* edges = (const int*)d_in[20];

  float* ws = (float*)d_ws;
  float* c1 = ws;                  // 64*32*784   = 1,605,632
  float* p1w = ws + 1605632;       // 64*32*144   =   294,912
  float* c3 = ws + 1900544;        // 64*64*64    =   262,144
  float* emb = ws + 2162688;       // 64*256
  float* pcw = ws + 2179072;
  float* lpcw = ws + 2186752;
  float* l1mw = ws + 2194432;
  float* lcatw = ws + 2202112;     // ends 2204416
  float* lw = ws + 2204416;        // 64*256
  float* exx = ws + 2220800;       // 64*256 -> ends 2237184
  float* part = ws + 2237184;      // 64*2*32*576 = 2,359,296
  float* outp = (float*)d_out;

  k_conv1<<<dim3(4, 64), dim3(512), 0, stream>>>(image, cw1, cb1, c1);
  k_conv2a<<<dim3(4, 2, 64), dim3(1024), 0, stream>>>(c1, cw2, part);
  k_conv2b<<<dim3(1152), dim3(256), 0, stream>>>(part, cb2, p1w);
  k_conv3<<<dim3(8, 64), dim3(256), 0, stream>>>(p1w, cw3, cb3, c3);
  k_conv4<<<dim3(8, 64), dim3(256), 0, stream>>>(c3, cw4, cb4, emb);
  k_heads<<<dim3(2, 64), dim3(256), 0, stream>>>(emb, wc1, bc1, wc2, bc2,
                                                 we1, be1, we2, be2,
                                                 pcw, lpcw, l1mw, lcatw);
  k_mc1<<<dim3(4, 64), dim3(64), 0, stream>>>(enoise, us, udn, edges,
                                              pcw, lpcw, l1mw, lcatw, lw, exx);
  k_mc2<<<dim3(64), dim3(256), 0, stream>>>(lw, exx, outp);
}

// Round 10
// 124.178 us; speedup vs baseline: 1.0110x; 1.0110x over previous
//
#include <hip/hip_runtime.h>

typedef unsigned long long u64;
#define EPSF 1e-6f

// ---------------- K1: conv1 1->32ch, 32x32 -> 28x28 ----------------
__global__ __launch_bounds__(512) void k_conv1(const float* __restrict__ img,
                                               const float* __restrict__ cw1,
                                               const float* __restrict__ cb1,
                                               float* __restrict__ c1) {
  int slab = blockIdx.x, b = blockIdx.y;
  __shared__ float simg[32 * 33];
  for (int k = threadIdx.x; k < 1024; k += 512) {
    int y = k >> 5, x = k & 31;
    simg[y * 33 + x] = img[b * 1024 + k];
  }
  int half = threadIdx.x >> 8;
  int u = threadIdx.x & 255;
  int ocl = u >> 5;
  int x = u & 31;
  int oc = slab * 8 + ocl;
  int y0 = half * 14;
  float w[25];
#pragma unroll
  for (int k = 0; k < 25; ++k) w[k] = cw1[oc * 25 + k];
  float bias = cb1[oc];
  __syncthreads();
  if (x < 28) {
    float acc[5];
#pragma unroll
    for (int k = 0; k < 5; ++k) acc[k] = bias;
    float* outp = c1 + (b * 32 + oc) * 784 + x;
#pragma unroll
    for (int rr = 0; rr < 18; ++rr) {
      int r = y0 + rr;
      float in[5];
#pragma unroll
      for (int c = 0; c < 5; ++c) in[c] = simg[r * 33 + x + c];
#pragma unroll
      for (int ky = 0; ky < 5; ++ky) {
        if (rr < ky || rr - ky > 13) continue;
        int slot = (rr - ky) % 5;
#pragma unroll
        for (int kx = 0; kx < 5; ++kx)
          acc[slot] = fmaf(w[ky * 5 + kx], in[kx], acc[slot]);
      }
      if (rr >= 4) {
        int slot = (rr - 4) % 5;
        outp[(y0 + rr - 4) * 28] = acc[slot];
        acc[slot] = bias;
      }
    }
  }
}

// ---------------- K2: conv2 32->32ch + 2x2 maxpool -> 12x12 (monolithic) -------
// grid (4 ocq of 8 oc, 64 img) = 256 blocks, 1024 threads = 16 waves.
// Full image in LDS (stride 29) + WEIGHTS IN LDS (transposed, wave-uniform
// ds_read_b64 broadcast). Main loop is DS-only -> in-order lgkmcnt queue ->
// fine-grained pipelining (no SMEM/DS lgkmcnt(0) drains).
// Wave = (opair: 4 of 2 oc) x (icq: 4 of 8 ic). Lane = 3x3 patch.
__global__ __launch_bounds__(1024) void k_conv2(const float* __restrict__ c1,
                                                const float* __restrict__ cw2,
                                                const float* __restrict__ cb2,
                                                float* __restrict__ p1w) {
  int ocq = blockIdx.x, b = blockIdx.y;
  __shared__ float smem[32384];   // 129.5KB: cimg[32][28x29]=25984 | w2s 6400
  float* w2s = smem + 25984;      // [(ic*25+kk)*8 + o]
  int t = threadIdx.x;
  {  // stage weights transposed (coalesced float4 reads)
    const float4* src = (const float4*)(cw2 + ocq * 8 * 800);
    for (int k4 = t; k4 < 1600; k4 += 1024) {
      float4 v = src[k4];
      float vv[4] = {v.x, v.y, v.z, v.w};
      int k = k4 * 4;
#pragma unroll
      for (int r = 0; r < 4; ++r) {
        int kk = k + r;
        int o = kk / 800, rest = kk % 800;
        w2s[rest * 8 + o] = vv[r];
      }
    }
  }
  if (t < 784) {                  // conflict-free scalar staging of the image
    int row = t / 28, col = t % 28;
    int lofs = row * 29 + col;
    const float* src = c1 + (size_t)b * 25088 + t;
#pragma unroll
    for (int ic = 0; ic < 32; ++ic) smem[ic * 812 + lofs] = src[ic * 784];
  }
  int w = __builtin_amdgcn_readfirstlane(t >> 6);   // wave id
  int opair = w & 3;              // oc pair within the 8-oc slab
  int icq = w >> 2;               // ic quarter: 8 ic each
  int l = t & 63;
  int py = l >> 3, px = l & 7;    // 3x3 patch origin (3py, 3px)
  int oc0 = ocq * 8 + opair * 2;
  float acc[2][9];
#pragma unroll
  for (int j = 0; j < 2; ++j)
#pragma unroll
    for (int e = 0; e < 9; ++e) acc[j][e] = 0.f;
  __syncthreads();

  const float* base0 = smem + icq * 8 * 812 + (3 * py) * 29 + 3 * px;
  const float* wbase = w2s + (size_t)icq * 8 * 200 + opair * 2;  // + (ic*25+k)*8
#pragma unroll
  for (int ic = 0; ic < 8; ++ic) {
    float wa[25], wb[25];
#pragma unroll
    for (int k = 0; k < 25; ++k) {   // wave-uniform ds_read_b64 broadcast
      float2 wv = *(const float2*)(wbase + (ic * 25 + k) * 8);
      wa[k] = wv.x; wb[k] = wv.y;
    }
    const float* base = base0 + ic * 812;
#pragma unroll
    for (int rr = 0; rr < 7; ++rr) {
      float win[7];
#pragma unroll
      for (int m = 0; m < 7; ++m) win[m] = base[rr * 29 + m];
#pragma unroll
      for (int i = 0; i < 3; ++i) {
        if (i > rr || rr - i > 4) continue;  // compile-time pruned
        int ky = rr - i;
#pragma unroll
        for (int kx = 0; kx < 5; ++kx) {
#pragma unroll
          for (int jj = 0; jj < 3; ++jj) {
            acc[0][i * 3 + jj] = fmaf(wa[ky * 5 + kx], win[jj + kx], acc[0][i * 3 + jj]);
            acc[1][i * 3 + jj] = fmaf(wb[ky * 5 + kx], win[jj + kx], acc[1][i * 3 + jj]);
          }
        }
      }
    }
  }

  __syncthreads();   // compute done -> cimg dead, safe to alias
  float* slots = smem;           // 2 slots x 4608 (icq2 -> slot0, icq3 -> slot1)
  float* cbuf = smem + 9216;     // [8 oc][24][24]
  int chunk = opair * 2 * 576 + l * 9;   // lane stride 9 -> 2-way banks (free)
  if (icq >= 2) {
    float* d = slots + (icq - 2) * 4608 + chunk;
#pragma unroll
    for (int j = 0; j < 2; ++j)
#pragma unroll
      for (int e = 0; e < 9; ++e) d[j * 576 + e] = acc[j][e];
  }
  __syncthreads();
  if (icq < 2) {
    const float* s = slots + icq * 4608 + chunk;
#pragma unroll
    for (int j = 0; j < 2; ++j)
#pragma unroll
      for (int e = 0; e < 9; ++e) acc[j][e] += s[j * 576 + e];
  }
  __syncthreads();
  if (icq == 1) {
    float* d = slots + chunk;
#pragma unroll
    for (int j = 0; j < 2; ++j)
#pragma unroll
      for (int e = 0; e < 9; ++e) d[j * 576 + e] = acc[j][e];
  }
  __syncthreads();
  if (icq == 0) {
    const float* s = slots + chunk;
#pragma unroll
    for (int j = 0; j < 2; ++j) {
      float bias = cb2[oc0 + j];
#pragma unroll
      for (int i = 0; i < 3; ++i)
#pragma unroll
        for (int jj = 0; jj < 3; ++jj)
          cbuf[(opair * 2 + j) * 576 + (3 * py + i) * 24 + 3 * px + jj] =
              acc[j][i * 3 + jj] + s[j * 576 + i * 3 + jj] + bias;
    }
  }
  __syncthreads();
  // fused 2x2 maxpool -> p1w[img][32][12][12]
  for (int k = t; k < 1152; k += 1024) {
    int o = k / 144, rem = k % 144;
    int PY = rem / 12, PX = rem % 12;
    const float* b0 = cbuf + o * 576 + (2 * PY) * 24 + 2 * PX;
    float m = fmaxf(fmaxf(b0[0], b0[1]), fmaxf(b0[24], b0[25]));
    p1w[((size_t)b * 32 + ocq * 8 + o) * 144 + PY * 12 + PX] = m;
  }
}

// ---------------- K3: conv3 32->64ch, 12x12 -> 8x8 ----------------
__global__ __launch_bounds__(256) void k_conv3(const float* __restrict__ p1w,
                                               const float* __restrict__ cw3,
                                               const float* __restrict__ cb3,
                                               float* __restrict__ c3) {
  int oc8 = blockIdx.x, b = blockIdx.y;
  __shared__ float smem[11008];
  float* w3s = smem;
  float* ins = smem + 6400;
  int t = threadIdx.x;
  {
    const float4* src = (const float4*)(p1w + b * 32 * 144);
    float4* dst = (float4*)ins;
    for (int k = t; k < 1152; k += 256) dst[k] = src[k];
  }
  {
    const float4* src = (const float4*)(cw3 + oc8 * 8 * 800);
    for (int k4 = t; k4 < 1600; k4 += 256) {
      float4 v = src[k4];
      float vv[4] = {v.x, v.y, v.z, v.w};
      int k = k4 * 4;
#pragma unroll
      for (int r = 0; r < 4; ++r) {
        int kk = k + r;
        int o = kk / 800, rest = kk % 800;
        w3s[rest * 8 + o] = vv[r];
      }
    }
  }
  int g = t >> 4, p = t & 15;
  int ocg = p >> 3, row = p & 7;
  float acc[4][8];
#pragma unroll
  for (int j = 0; j < 4; ++j)
#pragma unroll
    for (int c = 0; c < 8; ++c) acc[j][c] = 0.f;
  __syncthreads();
#pragma unroll
  for (int icl = 0; icl < 2; ++icl) {
    int ic = g + icl * 16;
#pragma unroll
    for (int ky = 0; ky < 5; ++ky) {
      const float4* rp = (const float4*)(ins + ic * 144 + (row + ky) * 12);
      float win[12];
#pragma unroll
      for (int q = 0; q < 3; ++q) {
        float4 v = rp[q];
        win[4 * q] = v.x; win[4 * q + 1] = v.y; win[4 * q + 2] = v.z; win[4 * q + 3] = v.w;
      }
      const float* wb = w3s + (ic * 25 + ky * 5) * 8 + ocg * 4;
#pragma unroll
      for (int kx = 0; kx < 5; ++kx) {
        float wq[4];
        *(float4*)wq = *(const float4*)(wb + kx * 8);
#pragma unroll
        for (int c = 0; c < 8; ++c) {
#pragma unroll
          for (int j = 0; j < 4; ++j) acc[j][c] = fmaf(wq[j], win[c + kx], acc[j][c]);
        }
      }
    }
  }
  float* buf = smem;
  __syncthreads();
  if (g >= 8) {
    float* d = buf + (g - 8) * 512 + p * 32;
#pragma unroll
    for (int j = 0; j < 4; ++j)
#pragma unroll
      for (int c = 0; c < 8; ++c) d[j * 8 + c] = acc[j][c];
  }
  __syncthreads();
  if (g < 8) {
    const float* s = buf + g * 512 + p * 32;
#pragma unroll
    for (int j = 0; j < 4; ++j)
#pragma unroll
      for (int c = 0; c < 8; ++c) acc[j][c] += s[j * 8 + c];
  }
  __syncthreads();
  if (g >= 4 && g < 8) {
    float* d = buf + (g - 4) * 512 + p * 32;
#pragma unroll
    for (int j = 0; j < 4; ++j)
#pragma unroll
      for (int c = 0; c < 8; ++c) d[j * 8 + c] = acc[j][c];
  }
  __syncthreads();
  if (g < 4) {
    const float* s = buf + g * 512 + p * 32;
#pragma unroll
    for (int j = 0; j < 4; ++j)
#pragma unroll
      for (int c = 0; c < 8; ++c) acc[j][c] += s[j * 8 + c];
  }
  __syncthreads();
  if (g == 2 || g == 3) {
    float* d = buf + (g - 2) * 512 + p * 32;
#pragma unroll
    for (int j = 0; j < 4; ++j)
#pragma unroll
      for (int c = 0; c < 8; ++c) d[j * 8 + c] = acc[j][c];
  }
  __syncthreads();
  if (g < 2) {
    const float* s = buf + g * 512 + p * 32;
#pragma unroll
    for (int j = 0; j < 4; ++j)
#pragma unroll
      for (int c = 0; c < 8; ++c) acc[j][c] += s[j * 8 + c];
  }
  __syncthreads();
  if (g == 1) {
    float* d = buf + p * 32;
#pragma unroll
    for (int j = 0; j < 4; ++j)
#pragma unroll
      for (int c = 0; c < 8; ++c) d[j * 8 + c] = acc[j][c];
  }
  __syncthreads();
  if (g == 0) {
    const float* s = buf + p * 32;
#pragma unroll
    for (int j = 0; j < 4; ++j) {
      float bias = cb3[oc8 * 8 + ocg * 4 + j];
      float4 v0, v1;
      v0.x = acc[j][0] + s[j * 8 + 0] + bias; v0.y = acc[j][1] + s[j * 8 + 1] + bias;
      v0.z = acc[j][2] + s[j * 8 + 2] + bias; v0.w = acc[j][3] + s[j * 8 + 3] + bias;
      v1.x = acc[j][4] + s[j * 8 + 4] + bias; v1.y = acc[j][5] + s[j * 8 + 5] + bias;
      v1.z = acc[j][6] + s[j * 8 + 6] + bias; v1.w = acc[j][7] + s[j * 8 + 7] + bias;
      float* op = c3 + (b * 64 + oc8 * 8 + ocg * 4 + j) * 64 + row * 8;
      *(float4*)op = v0; *(float4*)(op + 4) = v1;
    }
  }
}

// ---------------- K4: conv4 64->64ch, 8x8 -> 4x4, fused pool -> emb[256] ----------------
__global__ __launch_bounds__(256) void k_conv4(const float* __restrict__ c3,
                                               const float* __restrict__ cw4,
                                               const float* __restrict__ cb4,
                                               float* __restrict__ emb) {
  int oc8 = blockIdx.x, b = blockIdx.y;
  __shared__ float smem[17152];
  float* w4s = smem;
  float* ins = smem + 12800;
  int t = threadIdx.x;
  {
    const float4* src = (const float4*)(c3 + b * 4096);
    for (int k = t; k < 1024; k += 256) {
      int ic = k >> 4, q = k & 15;
      *(float4*)(ins + ic * 68 + q * 4) = src[k];
    }
  }
  {
    const float4* src = (const float4*)(cw4 + oc8 * 8 * 1600);
    for (int k4 = t; k4 < 3200; k4 += 256) {
      float4 v = src[k4];
      float vv[4] = {v.x, v.y, v.z, v.w};
      int k = k4 * 4;
#pragma unroll
      for (int r = 0; r < 4; ++r) {
        int kk = k + r;
        int o = kk / 1600, rest = kk % 1600;
        w4s[rest * 8 + o] = vv[r];
      }
    }
  }
  int g = t >> 3, p = t & 7;
  int ocg = p >> 2, row = p & 3;
  float acc[4][4];
#pragma unroll
  for (int j = 0; j < 4; ++j)
#pragma unroll
    for (int c = 0; c < 4; ++c) acc[j][c] = 0.f;
  __syncthreads();
#pragma unroll
  for (int icl = 0; icl < 2; ++icl) {
    int ic = g + icl * 32;
#pragma unroll
    for (int ky = 0; ky < 5; ++ky) {
      const float4* rp = (const float4*)(ins + ic * 68 + (row + ky) * 8);
      float win[8];
#pragma unroll
      for (int q = 0; q < 2; ++q) {
        float4 v = rp[q];
        win[4 * q] = v.x; win[4 * q + 1] = v.y; win[4 * q + 2] = v.z; win[4 * q + 3] = v.w;
      }
      const float* wb = w4s + (ic * 25 + ky * 5) * 8 + ocg * 4;
#pragma unroll
      for (int kx = 0; kx < 5; ++kx) {
        float wq[4];
        *(float4*)wq = *(const float4*)(wb + kx * 8);
#pragma unroll
        for (int c = 0; c < 4; ++c) {
#pragma unroll
          for (int j = 0; j < 4; ++j) acc[j][c] = fmaf(wq[j], win[c + kx], acc[j][c]);
        }
      }
    }
  }
  float* buf = smem;
#pragma unroll
  for (int half = 16; half >= 1; half >>= 1) {
    __syncthreads();
    if (g >= half && g < 2 * half) {
      float* d = buf + (g - half) * 128 + p * 16;
#pragma unroll
      for (int j = 0; j < 4; ++j)
#pragma unroll
        for (int c = 0; c < 4; ++c) d[j * 4 + c] = acc[j][c];
    }
    __syncthreads();
    if (g < half) {
      const float* s = buf + g * 128 + p * 16;
#pragma unroll
      for (int j = 0; j < 4; ++j)
#pragma unroll
        for (int c = 0; c < 4; ++c) acc[j][c] += s[j * 4 + c];
    }
  }
  float* pb = buf + 2048;
  if (g == 0) {
#pragma unroll
    for (int j = 0; j < 4; ++j) {
      float bias = cb4[oc8 * 8 + ocg * 4 + j];
#pragma unroll
      for (int c = 0; c < 4; ++c) pb[(ocg * 4 + j) * 16 + row * 4 + c] = acc[j][c] + bias;
    }
  }
  __syncthreads();
  if (t < 32) {
    int o = t >> 2, q = t & 3, py = q >> 1, px = q & 1;
    const float* b0 = pb + o * 16 + (2 * py) * 4 + 2 * px;
    float m = fmaxf(fmaxf(b0[0], b0[1]), fmaxf(b0[4], b0[5]));
    emb[b * 256 + (oc8 * 8 + o) * 4 + py * 2 + px] = m;
  }
}

// ---------------- K5a: MLP heads ----------------
__global__ __launch_bounds__(256) void k_heads(const float* __restrict__ emb,
    const float* __restrict__ wc1, const float* __restrict__ bc1,
    const float* __restrict__ wc2, const float* __restrict__ bc2,
    const float* __restrict__ we1, const float* __restrict__ be1,
    const float* __restrict__ we2, const float* __restrict__ be2,
    float* __restrict__ pcw, float* __restrict__ lpcw,
    float* __restrict__ l1mw, float* __restrict__ lcatw) {
  int head = blockIdx.x, b = blockIdx.y;
  int t = threadIdx.x;
  __shared__ float e_s[256], h_s[256];
  __shared__ float aux;
  e_s[t] = emb[b * 256 + t];
  __syncthreads();
  const float* W1 = head ? we1 : wc1;
  const float* B1 = head ? be1 : bc1;
  float s = B1[t];
  for (int i = 0; i < 256; i += 4) {
    s = fmaf(e_s[i], W1[i * 256 + t], s);
    s = fmaf(e_s[i + 1], W1[(i + 1) * 256 + t], s);
    s = fmaf(e_s[i + 2], W1[(i + 2) * 256 + t], s);
    s = fmaf(e_s[i + 3], W1[(i + 3) * 256 + t], s);
  }
  h_s[t] = fmaxf(s, 0.f);
  __syncthreads();
  int NO = head ? 36 : 120;
  const float* W2 = head ? we2 : wc2;
  const float* B2 = head ? be2 : bc2;
  if (t < NO) {
    float s2 = B2[t];
    for (int i = 0; i < 256; ++i) s2 = fmaf(h_s[i], W2[i * NO + t], s2);
    float p = 1.f / (1.f + expf(-s2));
    p = fminf(fmaxf(p, EPSF), 1.f - EPSF);
    if (head == 0) {
      pcw[b * 120 + t] = p;
      lpcw[b * 120 + t] = logf(p);
      l1mw[b * 120 + t] = log1pf(-p);
    } else {
      e_s[t] = p;
    }
  }
  if (head == 1) {
    __syncthreads();
    if (t == 0) {
      float sm = 0.f;
      for (int j2 = 0; j2 < 36; ++j2) sm += e_s[j2];
      aux = sm;
    }
    __syncthreads();
    if (t < 36) lcatw[b * 36 + t] = logf(e_s[t] / aux);
  }
}

// ---------------- K5b: per-sample pass ----------------
__global__ __launch_bounds__(64) void k_mc1(const float* __restrict__ enoise,
    const float* __restrict__ us, const float* __restrict__ ud,
    const int* __restrict__ edges,
    const float* __restrict__ pcw, const float* __restrict__ lpcw,
    const float* __restrict__ l1mw, const float* __restrict__ lcatw,
    float* __restrict__ lw, float* __restrict__ exx) {
  int chunk = blockIdx.x, b = blockIdx.y, t = threadIdx.x;
  int s = chunk * 64 + t;
  __shared__ __align__(16) float pc_s[120];
  __shared__ __align__(16) float lpc_s[120];
  __shared__ __align__(16) float l1m_s[120];
  __shared__ __align__(16) float lcat_s[36];
  __shared__ __align__(16) int einfo[120];
  for (int k = t; k < 120; k += 64) {
    pc_s[k] = pcw[b * 120 + k];
    lpc_s[k] = lpcw[b * 120 + k];
    l1m_s[k] = l1mw[b * 120 + k];
    int u = edges[2 * k], v = edges[2 * k + 1];
    int d = v - u;
    int isV = (d == 6 || d == -6) ? 1 : 0;
    int pos = d > 0 ? u : v;
    einfo[k] = pos | (isV << 6);
  }
  if (t < 36) lcat_s[t] = lcatw[b * 36 + t];
  __syncthreads();

  float logw = 0.f;
  u64 H = 0, V = 0;
  {
    const float4* np = (const float4*)(enoise + ((size_t)(b * 256 + s)) * 120);
#pragma unroll
    for (int q = 0; q < 30; ++q) {
      float4 nz = np[q];
      float4 p4 = ((const float4*)pc_s)[q];
      float4 lp4 = ((const float4*)lpc_s)[q];
      float4 lm4 = ((const float4*)l1m_s)[q];
      int4 e4 = ((const int4*)einfo)[q];
      float nv[4] = {nz.x, nz.y, nz.z, nz.w};
      float pv[4] = {p4.x, p4.y, p4.z, p4.w};
      float lv[4] = {lp4.x, lp4.y, lp4.z, lp4.w};
      float mv[4] = {lm4.x, lm4.y, lm4.z, lm4.w};
      int ev[4] = {e4.x, e4.y, e4.z, e4.w};
#pragma unroll
      for (int r = 0; r < 4; ++r) {
        bool conn = nv[r] < pv[r];
        logw += conn ? lv[r] : mv[r];
        if (conn) {
          u64 bit = 1ull << (ev[r] & 63);
          if (ev[r] & 64) V |= bit; else H |= bit;
        }
      }
    }
  }
  int si = 0, di = 0;
  {
    const float4* up = (const float4*)(us + ((size_t)(b * 256 + s)) * 36);
    float best = -1e30f;
#pragma unroll
    for (int q = 0; q < 9; ++q) {
      float4 uv = up[q];
      float4 lc4 = ((const float4*)lcat_s)[q];
      float vv[4] = {uv.x, uv.y, uv.z, uv.w};
      float lc[4] = {lc4.x, lc4.y, lc4.z, lc4.w};
#pragma unroll
      for (int r = 0; r < 4; ++r) {
        float u = fminf(fmaxf(vv[r], EPSF), 1.f - EPSF);
        float gq = -logf(-logf(u));
        float val = lc[r] + gq;
        if (val > best) { best = val; si = q * 4 + r; }
      }
    }
  }
  {
    const float4* up = (const float4*)(ud + ((size_t)(b * 256 + s)) * 36);
    float best = -1e30f;
#pragma unroll
    for (int q = 0; q < 9; ++q) {
      float4 uv = up[q];
      float4 lc4 = ((const float4*)lcat_s)[q];
      float vv[4] = {uv.x, uv.y, uv.z, uv.w};
      float lc[4] = {lc4.x, lc4.y, lc4.z, lc4.w};
#pragma unroll
      for (int r = 0; r < 4; ++r) {
        float u = fminf(fmaxf(vv[r], EPSF), 1.f - EPSF);
        float gq = -logf(-logf(u));
        float val = lc[r] + gq;
        if (val > best) { best = val; di = q * 4 + r; }
      }
    }
  }
  logw += lcat_s[si] + lcat_s[di];

  u64 comp = 1ull << si;
  while (true) {
    u64 prev = comp;
    comp |= ((comp & H) << 1) | ((comp >> 1) & H);
    comp |= ((comp & V) << 6) | ((comp >> 6) & V);
    if (comp == prev) break;
  }
  float ex;
  if (si == di) ex = (comp != (1ull << si)) ? 1.f : 0.f;
  else ex = ((comp >> di) & 1ull) ? 1.f : 0.f;

  lw[b * 256 + s] = logw;
  exx[b * 256 + s] = ex;
}

// ---------------- K5c: softmax over samples -> output ----------------
__global__ __launch_bounds__(256) void k_mc2(const float* __restrict__ lw,
                                             const float* __restrict__ exx,
                                             float* __restrict__ out) {
  int b = blockIdx.x, t = threadIdx.x;
  __shared__ float red_s[256];
  float logw = lw[b * 256 + t];
  float ex = exx[b * 256 + t];
  red_s[t] = logw; __syncthreads();
  for (int off = 128; off > 0; off >>= 1) {
    if (t < off) red_s[t] = fmaxf(red_s[t], red_s[t + off]);
    __syncthreads();
  }
  float m = red_s[0]; __syncthreads();
  float evx = expf(logw - m);
  red_s[t] = evx; __syncthreads();
  for (int off = 128; off > 0; off >>= 1) {
    if (t < off) red_s[t] += red_s[t + off];
    __syncthreads();
  }
  float den = red_s[0]; __syncthreads();
  red_s[t] = evx * ex; __syncthreads();
  for (int off = 128; off > 0; off >>= 1) {
    if (t < off) red_s[t] += red_s[t + off];
    __syncthreads();
  }
  if (t == 0) {
    float p1v = red_s[0] / den;
    out[b * 2] = 1.f - p1v;
    out[b * 2 + 1] = p1v;
  }
}

extern "C" void kernel_launch(void* const* d_in, const int* in_sizes, int n_in,
                              void* d_out, int out_size, void* d_ws, size_t ws_size,
                              hipStream_t stream) {
  const float* image = (const float*)d_in[0];
  const float* enoise = (const float*)d_in[1];
  const float* us = (const float*)d_in[2];
  const float* udn = (const float*)d_in[3];
  const float* cw1 = (const float*)d_in[4];
  const float* cb1 = (const float*)d_in[5];
  const float* cw2 = (const float*)d_in[6];
  const float* cb2 = (const float*)d_in[7];
  const float* cw3 = (const float*)d_in[8];
  const float* cb3 = (const float*)d_in[9];
  const float* cw4 = (const float*)d_in[10];
  const float* cb4 = (const float*)d_in[11];
  const float* wc1 = (const float*)d_in[12];
  const float* bc1 = (const float*)d_in[13];
  const float* wc2 = (const float*)d_in[14];
  const float* bc2 = (const float*)d_in[15];
  const float* we1 = (const float*)d_in[16];
  const float* be1 = (const float*)d_in[17];
  const float* we2 = (const float*)d_in[18];
  const float* be2 = (const float*)d_in[19];
  const int* edges = (const int*)d_in[20];

  float* ws = (float*)d_ws;
  float* c1 = ws;                  // 64*32*784
  float* p1w = ws + 1605632;       // 64*32*144
  float* c3 = ws + 1900544;        // 64*64*64
  float* emb = ws + 2162688;       // 64*256
  float* pcw = ws + 2179072;
  float* lpcw = ws + 2186752;
  float* l1mw = ws + 2194432;
  float* lcatw = ws + 2202112;     // ends 2204416
  float* lw = ws + 2204416;        // 64*256
  float* exx = ws + 2220800;       // 64*256
  float* outp = (float*)d_out;

  k_conv1<<<dim3(4, 64), dim3(512), 0, stream>>>(image, cw1, cb1, c1);
  k_conv2<<<dim3(4, 64), dim3(1024), 0, stream>>>(c1, cw2, cb2, p1w);
  k_conv3<<<dim3(8, 64), dim3(256), 0, stream>>>(p1w, cw3, cb3, c3);
  k_conv4<<<dim3(8, 64), dim3(256), 0, stream>>>(c3, cw4, cb4, emb);
  k_heads<<<dim3(2, 64), dim3(256), 0, stream>>>(emb, wc1, bc1, wc2, bc2,
                                                 we1, be1, we2, be2,
                                                 pcw, lpcw, l1mw, lcatw);
  k_mc1<<<dim3(4, 64), dim3(64), 0, stream>>>(enoise, us, udn, edges,
                                              pcw, lpcw, l1mw, lcatw, lw, exx);
  k_mc2<<<dim3(64), dim3(256), 0, stream>>>(lw, exx, outp);
}

// Round 11
// 119.621 us; speedup vs baseline: 1.0496x; 1.0381x over previous
//
#include <hip/hip_runtime.h>

typedef unsigned long long u64;
#define EPSF 1e-6f

// ---------------- K1: conv1 1->32ch, 32x32 -> 28x28 ----------------
__global__ __launch_bounds__(512) void k_conv1(const float* __restrict__ img,
                                               const float* __restrict__ cw1,
                                               const float* __restrict__ cb1,
                                               float* __restrict__ c1) {
  int slab = blockIdx.x, b = blockIdx.y;
  __shared__ float simg[32 * 33];
  for (int k = threadIdx.x; k < 1024; k += 512) {
    int y = k >> 5, x = k & 31;
    simg[y * 33 + x] = img[b * 1024 + k];
  }
  int half = threadIdx.x >> 8;
  int u = threadIdx.x & 255;
  int ocl = u >> 5;
  int x = u & 31;
  int oc = slab * 8 + ocl;
  int y0 = half * 14;
  float w[25];
#pragma unroll
  for (int k = 0; k < 25; ++k) w[k] = cw1[oc * 25 + k];
  float bias = cb1[oc];
  __syncthreads();
  if (x < 28) {
    float acc[5];
#pragma unroll
    for (int k = 0; k < 5; ++k) acc[k] = bias;
    float* outp = c1 + (b * 32 + oc) * 784 + x;
#pragma unroll
    for (int rr = 0; rr < 18; ++rr) {
      int r = y0 + rr;
      float in[5];
#pragma unroll
      for (int c = 0; c < 5; ++c) in[c] = simg[r * 33 + x + c];
#pragma unroll
      for (int ky = 0; ky < 5; ++ky) {
        if (rr < ky || rr - ky > 13) continue;
        int slot = (rr - ky) % 5;
#pragma unroll
        for (int kx = 0; kx < 5; ++kx)
          acc[slot] = fmaf(w[ky * 5 + kx], in[kx], acc[slot]);
      }
      if (rr >= 4) {
        int slot = (rr - 4) % 5;
        outp[(y0 + rr - 4) * 28] = acc[slot];
        acc[slot] = bias;
      }
    }
  }
}

// ---------------- K2: conv2 32->32ch + 2x2 maxpool (monolithic) -------
// grid (4 ocq of 8 oc, 64 img) = 256 blocks, 1024 threads, launch_bounds(1024,4)
// -> VGPR cap 128 (no spill). Wave = (ocg: 2 of 4 oc) x (icq: 8 of 4 ic):
// window-read replication is 2x (vs 4x with 2-oc waves) -> LDS pipe unloaded.
// Weights in LDS, read per-ky as wave-uniform float4 broadcast (20 VGPR live).
// Full window 7x7 in regs (49) + acc[4][9] (36) ~= 110 VGPR.
__global__ __launch_bounds__(1024, 4) void k_conv2(const float* __restrict__ c1,
                                                   const float* __restrict__ cw2,
                                                   const float* __restrict__ cb2,
                                                   float* __restrict__ p1w) {
  int ocq = blockIdx.x, b = blockIdx.y;
  __shared__ float smem[32384];   // 129.5KB: cimg[32][28x29]=25984 | w2s 6400
  float* w2s = smem + 25984;      // [(ic*25+kk)*8 + o]
  int t = threadIdx.x;
  {  // stage weights transposed (coalesced float4 reads)
    const float4* src = (const float4*)(cw2 + ocq * 8 * 800);
    for (int k4 = t; k4 < 1600; k4 += 1024) {
      float4 v = src[k4];
      float vv[4] = {v.x, v.y, v.z, v.w};
      int k = k4 * 4;
#pragma unroll
      for (int r = 0; r < 4; ++r) {
        int kk = k + r;
        int o = kk / 800, rest = kk % 800;
        w2s[rest * 8 + o] = vv[r];
      }
    }
  }
  if (t < 784) {                  // conflict-free scalar staging of the image
    int row = t / 28, col = t % 28;
    int lofs = row * 29 + col;
    const float* src = c1 + (size_t)b * 25088 + t;
#pragma unroll
    for (int ic = 0; ic < 32; ++ic) smem[ic * 812 + lofs] = src[ic * 784];
  }
  int w = __builtin_amdgcn_readfirstlane(t >> 6);   // wave id
  int ocg = w & 1;                // 4-oc group within the 8-oc slab
  int icq = w >> 1;               // ic octant: 4 ic each
  int l = t & 63;
  int py = l >> 3, px = l & 7;    // 3x3 patch origin (3py, 3px)
  int oc0 = ocq * 8 + ocg * 4;
  float acc[4][9];
#pragma unroll
  for (int o = 0; o < 4; ++o)
#pragma unroll
    for (int e = 0; e < 9; ++e) acc[o][e] = 0.f;
  __syncthreads();

  const float* base0 = smem + icq * 4 * 812 + (3 * py) * 29 + 3 * px;
  const float* wk0 = w2s + icq * 800 + ocg * 4;   // + icl*200 + (ky*5+kx)*8
#pragma unroll
  for (int icl = 0; icl < 4; ++icl) {
    const float* base = base0 + icl * 812;
    float win[7][7];
#pragma unroll
    for (int rr = 0; rr < 7; ++rr)
#pragma unroll
      for (int m = 0; m < 7; ++m) win[rr][m] = base[rr * 29 + m];
    const float* wk = wk0 + icl * 200;
#pragma unroll
    for (int ky = 0; ky < 5; ++ky) {
      float wq[5][4];
#pragma unroll
      for (int kx = 0; kx < 5; ++kx)
        *(float4*)wq[kx] = *(const float4*)(wk + (ky * 5 + kx) * 8);
#pragma unroll
      for (int i = 0; i < 3; ++i) {
#pragma unroll
        for (int kx = 0; kx < 5; ++kx) {
#pragma unroll
          for (int jj = 0; jj < 3; ++jj) {
            float v = win[i + ky][jj + kx];
            acc[0][i * 3 + jj] = fmaf(wq[kx][0], v, acc[0][i * 3 + jj]);
            acc[1][i * 3 + jj] = fmaf(wq[kx][1], v, acc[1][i * 3 + jj]);
            acc[2][i * 3 + jj] = fmaf(wq[kx][2], v, acc[2][i * 3 + jj]);
            acc[3][i * 3 + jj] = fmaf(wq[kx][3], v, acc[3][i * 3 + jj]);
          }
        }
      }
    }
  }

  __syncthreads();   // compute done -> cimg dead, safe to alias
  float* slots = smem;           // 4 slots x 4608 floats (within dead cimg area)
  float* cbuf = smem + 18432;    // [8 oc][24][24]
  int chunk = ocg * 2304 + l * 9;   // + o*576 + e; lane stride 9 -> 2-way (free)
  // 8-way icq reduce tree: 8 -> 4 -> 2 -> 1
  if (icq >= 4) {
    float* d = slots + (icq - 4) * 4608 + chunk;
#pragma unroll
    for (int o = 0; o < 4; ++o)
#pragma unroll
      for (int e = 0; e < 9; ++e) d[o * 576 + e] = acc[o][e];
  }
  __syncthreads();
  if (icq < 4) {
    const float* s = slots + icq * 4608 + chunk;
#pragma unroll
    for (int o = 0; o < 4; ++o)
#pragma unroll
      for (int e = 0; e < 9; ++e) acc[o][e] += s[o * 576 + e];
  }
  __syncthreads();
  if (icq == 2 || icq == 3) {
    float* d = slots + (icq - 2) * 4608 + chunk;
#pragma unroll
    for (int o = 0; o < 4; ++o)
#pragma unroll
      for (int e = 0; e < 9; ++e) d[o * 576 + e] = acc[o][e];
  }
  __syncthreads();
  if (icq < 2) {
    const float* s = slots + icq * 4608 + chunk;
#pragma unroll
    for (int o = 0; o < 4; ++o)
#pragma unroll
      for (int e = 0; e < 9; ++e) acc[o][e] += s[o * 576 + e];
  }
  __syncthreads();
  if (icq == 1) {
    float* d = slots + chunk;
#pragma unroll
    for (int o = 0; o < 4; ++o)
#pragma unroll
      for (int e = 0; e < 9; ++e) d[o * 576 + e] = acc[o][e];
  }
  __syncthreads();
  if (icq == 0) {
    const float* s = slots + chunk;
#pragma unroll
    for (int o = 0; o < 4; ++o) {
      float bias = cb2[oc0 + o];
#pragma unroll
      for (int i = 0; i < 3; ++i)
#pragma unroll
        for (int jj = 0; jj < 3; ++jj)
          cbuf[(ocg * 4 + o) * 576 + (3 * py + i) * 24 + 3 * px + jj] =
              acc[o][i * 3 + jj] + s[o * 576 + i * 3 + jj] + bias;
    }
  }
  __syncthreads();
  // fused 2x2 maxpool -> p1w[img][32][12][12]
  for (int k = t; k < 1152; k += 1024) {
    int o = k / 144, rem = k % 144;
    int PY = rem / 12, PX = rem % 12;
    const float* b0 = cbuf + o * 576 + (2 * PY) * 24 + 2 * PX;
    float m = fmaxf(fmaxf(b0[0], b0[1]), fmaxf(b0[24], b0[25]));
    p1w[((size_t)b * 32 + ocq * 8 + o) * 144 + PY * 12 + PX] = m;
  }
}

// ---------------- K3: conv3 32->64ch, 12x12 -> 8x8 ----------------
__global__ __launch_bounds__(256) void k_conv3(const float* __restrict__ p1w,
                                               const float* __restrict__ cw3,
                                               const float* __restrict__ cb3,
                                               float* __restrict__ c3) {
  int oc8 = blockIdx.x, b = blockIdx.y;
  __shared__ float smem[11008];
  float* w3s = smem;
  float* ins = smem + 6400;
  int t = threadIdx.x;
  {
    const float4* src = (const float4*)(p1w + b * 32 * 144);
    float4* dst = (float4*)ins;
    for (int k = t; k < 1152; k += 256) dst[k] = src[k];
  }
  {
    const float4* src = (const float4*)(cw3 + oc8 * 8 * 800);
    for (int k4 = t; k4 < 1600; k4 += 256) {
      float4 v = src[k4];
      float vv[4] = {v.x, v.y, v.z, v.w};
      int k = k4 * 4;
#pragma unroll
      for (int r = 0; r < 4; ++r) {
        int kk = k + r;
        int o = kk / 800, rest = kk % 800;
        w3s[rest * 8 + o] = vv[r];
      }
    }
  }
  int g = t >> 4, p = t & 15;
  int ocg = p >> 3, row = p & 7;
  float acc[4][8];
#pragma unroll
  for (int j = 0; j < 4; ++j)
#pragma unroll
    for (int c = 0; c < 8; ++c) acc[j][c] = 0.f;
  __syncthreads();
#pragma unroll
  for (int icl = 0; icl < 2; ++icl) {
    int ic = g + icl * 16;
#pragma unroll
    for (int ky = 0; ky < 5; ++ky) {
      const float4* rp = (const float4*)(ins + ic * 144 + (row + ky) * 12);
      float win[12];
#pragma unroll
      for (int q = 0; q < 3; ++q) {
        float4 v = rp[q];
        win[4 * q] = v.x; win[4 * q + 1] = v.y; win[4 * q + 2] = v.z; win[4 * q + 3] = v.w;
      }
      const float* wb = w3s + (ic * 25 + ky * 5) * 8 + ocg * 4;
#pragma unroll
      for (int kx = 0; kx < 5; ++kx) {
        float wq[4];
        *(float4*)wq = *(const float4*)(wb + kx * 8);
#pragma unroll
        for (int c = 0; c < 8; ++c) {
#pragma unroll
          for (int j = 0; j < 4; ++j) acc[j][c] = fmaf(wq[j], win[c + kx], acc[j][c]);
        }
      }
    }
  }
  float* buf = smem;
  __syncthreads();
  if (g >= 8) {
    float* d = buf + (g - 8) * 512 + p * 32;
#pragma unroll
    for (int j = 0; j < 4; ++j)
#pragma unroll
      for (int c = 0; c < 8; ++c) d[j * 8 + c] = acc[j][c];
  }
  __syncthreads();
  if (g < 8) {
    const float* s = buf + g * 512 + p * 32;
#pragma unroll
    for (int j = 0; j < 4; ++j)
#pragma unroll
      for (int c = 0; c < 8; ++c) acc[j][c] += s[j * 8 + c];
  }
  __syncthreads();
  if (g >= 4 && g < 8) {
    float* d = buf + (g - 4) * 512 + p * 32;
#pragma unroll
    for (int j = 0; j < 4; ++j)
#pragma unroll
      for (int c = 0; c < 8; ++c) d[j * 8 + c] = acc[j][c];
  }
  __syncthreads();
  if (g < 4) {
    const float* s = buf + g * 512 + p * 32;
#pragma unroll
    for (int j = 0; j < 4; ++j)
#pragma unroll
      for (int c = 0; c < 8; ++c) acc[j][c] += s[j * 8 + c];
  }
  __syncthreads();
  if (g == 2 || g == 3) {
    float* d = buf + (g - 2) * 512 + p * 32;
#pragma unroll
    for (int j = 0; j < 4; ++j)
#pragma unroll
      for (int c = 0; c < 8; ++c) d[j * 8 + c] = acc[j][c];
  }
  __syncthreads();
  if (g < 2) {
    const float* s = buf + g * 512 + p * 32;
#pragma unroll
    for (int j = 0; j < 4; ++j)
#pragma unroll
      for (int c = 0; c < 8; ++c) acc[j][c] += s[j * 8 + c];
  }
  __syncthreads();
  if (g == 1) {
    float* d = buf + p * 32;
#pragma unroll
    for (int j = 0; j < 4; ++j)
#pragma unroll
      for (int c = 0; c < 8; ++c) d[j * 8 + c] = acc[j][c];
  }
  __syncthreads();
  if (g == 0) {
    const float* s = buf + p * 32;
#pragma unroll
    for (int j = 0; j < 4; ++j) {
      float bias = cb3[oc8 * 8 + ocg * 4 + j];
      float4 v0, v1;
      v0.x = acc[j][0] + s[j * 8 + 0] + bias; v0.y = acc[j][1] + s[j * 8 + 1] + bias;
      v0.z = acc[j][2] + s[j * 8 + 2] + bias; v0.w = acc[j][3] + s[j * 8 + 3] + bias;
      v1.x = acc[j][4] + s[j * 8 + 4] + bias; v1.y = acc[j][5] + s[j * 8 + 5] + bias;
      v1.z = acc[j][6] + s[j * 8 + 6] + bias; v1.w = acc[j][7] + s[j * 8 + 7] + bias;
      float* op = c3 + (b * 64 + oc8 * 8 + ocg * 4 + j) * 64 + row * 8;
      *(float4*)op = v0; *(float4*)(op + 4) = v1;
    }
  }
}

// ---------------- K4: conv4 64->64ch, 8x8 -> 4x4, fused pool -> emb[256] ----------------
__global__ __launch_bounds__(256) void k_conv4(const float* __restrict__ c3,
                                               const float* __restrict__ cw4,
                                               const float* __restrict__ cb4,
                                               float* __restrict__ emb) {
  int oc8 = blockIdx.x, b = blockIdx.y;
  __shared__ float smem[17152];
  float* w4s = smem;
  float* ins = smem + 12800;
  int t = threadIdx.x;
  {
    const float4* src = (const float4*)(c3 + b * 4096);
    for (int k = t; k < 1024; k += 256) {
      int ic = k >> 4, q = k & 15;
      *(float4*)(ins + ic * 68 + q * 4) = src[k];
    }
  }
  {
    const float4* src = (const float4*)(cw4 + oc8 * 8 * 1600);
    for (int k4 = t; k4 < 3200; k4 += 256) {
      float4 v = src[k4];
      float vv[4] = {v.x, v.y, v.z, v.w};
      int k = k4 * 4;
#pragma unroll
      for (int r = 0; r < 4; ++r) {
        int kk = k + r;
        int o = kk / 1600, rest = kk % 1600;
        w4s[rest * 8 + o] = vv[r];
      }
    }
  }
  int g = t >> 3, p = t & 7;
  int ocg = p >> 2, row = p & 3;
  float acc[4][4];
#pragma unroll
  for (int j = 0; j < 4; ++j)
#pragma unroll
    for (int c = 0; c < 4; ++c) acc[j][c] = 0.f;
  __syncthreads();
#pragma unroll
  for (int icl = 0; icl < 2; ++icl) {
    int ic = g + icl * 32;
#pragma unroll
    for (int ky = 0; ky < 5; ++ky) {
      const float4* rp = (const float4*)(ins + ic * 68 + (row + ky) * 8);
      float win[8];
#pragma unroll
      for (int q = 0; q < 2; ++q) {
        float4 v = rp[q];
        win[4 * q] = v.x; win[4 * q + 1] = v.y; win[4 * q + 2] = v.z; win[4 * q + 3] = v.w;
      }
      const float* wb = w4s + (ic * 25 + ky * 5) * 8 + ocg * 4;
#pragma unroll
      for (int kx = 0; kx < 5; ++kx) {
        float wq[4];
        *(float4*)wq = *(const float4*)(wb + kx * 8);
#pragma unroll
        for (int c = 0; c < 4; ++c) {
#pragma unroll
          for (int j = 0; j < 4; ++j) acc[j][c] = fmaf(wq[j], win[c + kx], acc[j][c]);
        }
      }
    }
  }
  float* buf = smem;
#pragma unroll
  for (int half = 16; half >= 1; half >>= 1) {
    __syncthreads();
    if (g >= half && g < 2 * half) {
      float* d = buf + (g - half) * 128 + p * 16;
#pragma unroll
      for (int j = 0; j < 4; ++j)
#pragma unroll
        for (int c = 0; c < 4; ++c) d[j * 4 + c] = acc[j][c];
    }
    __syncthreads();
    if (g < half) {
      const float* s = buf + g * 128 + p * 16;
#pragma unroll
      for (int j = 0; j < 4; ++j)
#pragma unroll
        for (int c = 0; c < 4; ++c) acc[j][c] += s[j * 4 + c];
    }
  }
  float* pb = buf + 2048;
  if (g == 0) {
#pragma unroll
    for (int j = 0; j < 4; ++j) {
      float bias = cb4[oc8 * 8 + ocg * 4 + j];
#pragma unroll
      for (int c = 0; c < 4; ++c) pb[(ocg * 4 + j) * 16 + row * 4 + c] = acc[j][c] + bias;
    }
  }
  __syncthreads();
  if (t < 32) {
    int o = t >> 2, q = t & 3, py = q >> 1, px = q & 1;
    const float* b0 = pb + o * 16 + (2 * py) * 4 + 2 * px;
    float m = fmaxf(fmaxf(b0[0], b0[1]), fmaxf(b0[4], b0[5]));
    emb[b * 256 + (oc8 * 8 + o) * 4 + py * 2 + px] = m;
  }
}

// ---------------- K5a: MLP heads ----------------
__global__ __launch_bounds__(256) void k_heads(const float* __restrict__ emb,
    const float* __restrict__ wc1, const float* __restrict__ bc1,
    const float* __restrict__ wc2, const float* __restrict__ bc2,
    const float* __restrict__ we1, const float* __restrict__ be1,
    const float* __restrict__ we2, const float* __restrict__ be2,
    float* __restrict__ pcw, float* __restrict__ lpcw,
    float* __restrict__ l1mw, float* __restrict__ lcatw) {
  int head = blockIdx.x, b = blockIdx.y;
  int t = threadIdx.x;
  __shared__ float e_s[256], h_s[256];
  __shared__ float aux;
  e_s[t] = emb[b * 256 + t];
  __syncthreads();
  const float* W1 = head ? we1 : wc1;
  const float* B1 = head ? be1 : bc1;
  float s = B1[t];
  for (int i = 0; i < 256; i += 4) {
    s = fmaf(e_s[i], W1[i * 256 + t], s);
    s = fmaf(e_s[i + 1], W1[(i + 1) * 256 + t], s);
    s = fmaf(e_s[i + 2], W1[(i + 2) * 256 + t], s);
    s = fmaf(e_s[i + 3], W1[(i + 3) * 256 + t], s);
  }
  h_s[t] = fmaxf(s, 0.f);
  __syncthreads();
  int NO = head ? 36 : 120;
  const float* W2 = head ? we2 : wc2;
  const float* B2 = head ? be2 : bc2;
  if (t < NO) {
    float s2 = B2[t];
    for (int i = 0; i < 256; ++i) s2 = fmaf(h_s[i], W2[i * NO + t], s2);
    float p = 1.f / (1.f + expf(-s2));
    p = fminf(fmaxf(p, EPSF), 1.f - EPSF);
    if (head == 0) {
      pcw[b * 120 + t] = p;
      lpcw[b * 120 + t] = logf(p);
      l1mw[b * 120 + t] = log1pf(-p);
    } else {
      e_s[t] = p;
    }
  }
  if (head == 1) {
    __syncthreads();
    if (t == 0) {
      float sm = 0.f;
      for (int j2 = 0; j2 < 36; ++j2) sm += e_s[j2];
      aux = sm;
    }
    __syncthreads();
    if (t < 36) lcatw[b * 36 + t] = logf(e_s[t] / aux);
  }
}

// ---------------- K5b: per-sample pass ----------------
__global__ __launch_bounds__(64) void k_mc1(const float* __restrict__ enoise,
    const float* __restrict__ us, const float* __restrict__ ud,
    const int* __restrict__ edges,
    const float* __restrict__ pcw, const float* __restrict__ lpcw,
    const float* __restrict__ l1mw, const float* __restrict__ lcatw,
    float* __restrict__ lw, float* __restrict__ exx) {
  int chunk = blockIdx.x, b = blockIdx.y, t = threadIdx.x;
  int s = chunk * 64 + t;
  __shared__ __align__(16) float pc_s[120];
  __shared__ __align__(16) float lpc_s[120];
  __shared__ __align__(16) float l1m_s[120];
  __shared__ __align__(16) float lcat_s[36];
  __shared__ __align__(16) int einfo[120];
  for (int k = t; k < 120; k += 64) {
    pc_s[k] = pcw[b * 120 + k];
    lpc_s[k] = lpcw[b * 120 + k];
    l1m_s[k] = l1mw[b * 120 + k];
    int u = edges[2 * k], v = edges[2 * k + 1];
    int d = v - u;
    int isV = (d == 6 || d == -6) ? 1 : 0;
    int pos = d > 0 ? u : v;
    einfo[k] = pos | (isV << 6);
  }
  if (t < 36) lcat_s[t] = lcatw[b * 36 + t];
  __syncthreads();

  float logw = 0.f;
  u64 H = 0, V = 0;
  {
    const float4* np = (const float4*)(enoise + ((size_t)(b * 256 + s)) * 120);
#pragma unroll
    for (int q = 0; q < 30; ++q) {
      float4 nz = np[q];
      float4 p4 = ((const float4*)pc_s)[q];
      float4 lp4 = ((const float4*)lpc_s)[q];
      float4 lm4 = ((const float4*)l1m_s)[q];
      int4 e4 = ((const int4*)einfo)[q];
      float nv[4] = {nz.x, nz.y, nz.z, nz.w};
      float pv[4] = {p4.x, p4.y, p4.z, p4.w};
      float lv[4] = {lp4.x, lp4.y, lp4.z, lp4.w};
      float mv[4] = {lm4.x, lm4.y, lm4.z, lm4.w};
      int ev[4] = {e4.x, e4.y, e4.z, e4.w};
#pragma unroll
      for (int r = 0; r < 4; ++r) {
        bool conn = nv[r] < pv[r];
        logw += conn ? lv[r] : mv[r];
        if (conn) {
          u64 bit = 1ull << (ev[r] & 63);
          if (ev[r] & 64) V |= bit; else H |= bit;
        }
      }
    }
  }
  int si = 0, di = 0;
  {
    const float4* up = (const float4*)(us + ((size_t)(b * 256 + s)) * 36);
    float best = -1e30f;
#pragma unroll
    for (int q = 0; q < 9; ++q) {
      float4 uv = up[q];
      float4 lc4 = ((const float4*)lcat_s)[q];
      float vv[4] = {uv.x, uv.y, uv.z, uv.w};
      float lc[4] = {lc4.x, lc4.y, lc4.z, lc4.w};
#pragma unroll
      for (int r = 0; r < 4; ++r) {
        float u = fminf(fmaxf(vv[r], EPSF), 1.f - EPSF);
        float gq = -logf(-logf(u));
        float val = lc[r] + gq;
        if (val > best) { best = val; si = q * 4 + r; }
      }
    }
  }
  {
    const float4* up = (const float4*)(ud + ((size_t)(b * 256 + s)) * 36);
    float best = -1e30f;
#pragma unroll
    for (int q = 0; q < 9; ++q) {
      float4 uv = up[q];
      float4 lc4 = ((const float4*)lcat_s)[q];
      float vv[4] = {uv.x, uv.y, uv.z, uv.w};
      float lc[4] = {lc4.x, lc4.y, lc4.z, lc4.w};
#pragma unroll
      for (int r = 0; r < 4; ++r) {
        float u = fminf(fmaxf(vv[r], EPSF), 1.f - EPSF);
        float gq = -logf(-logf(u));
        float val = lc[r] + gq;
        if (val > best) { best = val; di = q * 4 + r; }
      }
    }
  }
  logw += lcat_s[si] + lcat_s[di];

  u64 comp = 1ull << si;
  while (true) {
    u64 prev = comp;
    comp |= ((comp & H) << 1) | ((comp >> 1) & H);
    comp |= ((comp & V) << 6) | ((comp >> 6) & V);
    if (comp == prev) break;
  }
  float ex;
  if (si == di) ex = (comp != (1ull << si)) ? 1.f : 0.f;
  else ex = ((comp >> di) & 1ull) ? 1.f : 0.f;

  lw[b * 256 + s] = logw;
  exx[b * 256 + s] = ex;
}

// ---------------- K5c: softmax over samples -> output ----------------
__global__ __launch_bounds__(256) void k_mc2(const float* __restrict__ lw,
                                             const float* __restrict__ exx,
                                             float* __restrict__ out) {
  int b = blockIdx.x, t = threadIdx.x;
  __shared__ float red_s[256];
  float logw = lw[b * 256 + t];
  float ex = exx[b * 256 + t];
  red_s[t] = logw; __syncthreads();
  for (int off = 128; off > 0; off >>= 1) {
    if (t < off) red_s[t] = fmaxf(red_s[t], red_s[t + off]);
    __syncthreads();
  }
  float m = red_s[0]; __syncthreads();
  float evx = expf(logw - m);
  red_s[t] = evx; __syncthreads();
  for (int off = 128; off > 0; off >>= 1) {
    if (t < off) red_s[t] += red_s[t + off];
    __syncthreads();
  }
  float den = red_s[0]; __syncthreads();
  red_s[t] = evx * ex; __syncthreads();
  for (int off = 128; off > 0; off >>= 1) {
    if (t < off) red_s[t] += red_s[t + off];
    __syncthreads();
  }
  if (t == 0) {
    float p1v = red_s[0] / den;
    out[b * 2] = 1.f - p1v;
    out[b * 2 + 1] = p1v;
  }
}

extern "C" void kernel_launch(void* const* d_in, const int* in_sizes, int n_in,
                              void* d_out, int out_size, void* d_ws, size_t ws_size,
                              hipStream_t stream) {
  const float* image = (const float*)d_in[0];
  const float* enoise = (const float*)d_in[1];
  const float* us = (const float*)d_in[2];
  const float* udn = (const float*)d_in[3];
  const float* cw1 = (const float*)d_in[4];
  const float* cb1 = (const float*)d_in[5];
  const float* cw2 = (const float*)d_in[6];
  const float* cb2 = (const float*)d_in[7];
  const float* cw3 = (const float*)d_in[8];
  const float* cb3 = (const float*)d_in[9];
  const float* cw4 = (const float*)d_in[10];
  const float* cb4 = (const float*)d_in[11];
  const float* wc1 = (const float*)d_in[12];
  const float* bc1 = (const float*)d_in[13];
  const float* wc2 = (const float*)d_in[14];
  const float* bc2 = (const float*)d_in[15];
  const float* we1 = (const float*)d_in[16];
  const float* be1 = (const float*)d_in[17];
  const float* we2 = (const float*)d_in[18];
  const float* be2 = (const float*)d_in[19];
  const int* edges = (const int*)d_in[20];

  float* ws = (float*)d_ws;
  float* c1 = ws;                  // 64*32*784
  float* p1w = ws + 1605632;       // 64*32*144
  float* c3 = ws + 1900544;        // 64*64*64
  float* emb = ws + 2162688;       // 64*256
  float* pcw = ws + 2179072;
  float* lpcw = ws + 2186752;
  float* l1mw = ws + 2194432;
  float* lcatw = ws + 2202112;     // ends 2204416
  float* lw = ws + 2204416;        // 64*256
  float* exx = ws + 2220800;       // 64*256
  float* outp = (float*)d_out;

  k_conv1<<<dim3(4, 64), dim3(512), 0, stream>>>(image, cw1, cb1, c1);
  k_conv2<<<dim3(4, 64), dim3(1024), 0, stream>>>(c1, cw2, cb2, p1w);
  k_conv3<<<dim3(8, 64), dim3(256), 0, stream>>>(p1w, cw3, cb3, c3);
  k_conv4<<<dim3(8, 64), dim3(256), 0, stream>>>(c3, cw4, cb4, emb);
  k_heads<<<dim3(2, 64), dim3(256), 0, stream>>>(emb, wc1, bc1, wc2, bc2,
                                                 we1, be1, we2, be2,
                                                 pcw, lpcw, l1mw, lcatw);
  k_mc1<<<dim3(4, 64), dim3(64), 0, stream>>>(enoise, us, udn, edges,
                                              pcw, lpcw, l1mw, lcatw, lw, exx);
  k_mc2<<<dim3(64), dim3(256), 0, stream>>>(lw, exx, outp);
}